// Round 1
// 106.473 us; speedup vs baseline: 1.0020x; 1.0020x over previous
//
#include <hip/hip_runtime.h>

#define NSAMP 32
#define NELEM 307200          // 480*640 per sample
#define LAM 0.5f
#define EPS 1e-6f
#define BLOCKS_PER_SAMPLE 64
#define THREADS 256

typedef float f32x4 __attribute__((ext_vector_type(4)));

// ws layout: float4 per block, index [sample * 64 + chunk] = {sum_ld, sum_ld2, cnt, 0}

__device__ __forceinline__ void accum1(float p, float t, float& s1, float& s2, float& c) {
    const bool m = t > 0.f;
    const float ld = __logf(p + EPS) - __logf(t + EPS);
    s1 += m ? ld : 0.f;
    s2 += m ? ld * ld : 0.f;
    c  += m ? 1.f : 0.f;
}

__device__ __forceinline__ void accum4(f32x4 p, f32x4 t, float& s1, float& s2, float& c) {
    accum1(p.x, t.x, s1, s2, c);
    accum1(p.y, t.y, s1, s2, c);
    accum1(p.z, t.z, s1, s2, c);
    accum1(p.w, t.w, s1, s2, c);
}

__global__ __launch_bounds__(THREADS)
void sill_partial(const float* __restrict__ pred,
                  const float* __restrict__ targ,
                  float4* __restrict__ ws) {
    const int b     = blockIdx.y;   // sample
    const int chunk = blockIdx.x;   // chunk within sample
    const int tid   = threadIdx.x;

    const int f4_per_sample = NELEM / 4;                         // 76800
    const int f4_per_block  = f4_per_sample / BLOCKS_PER_SAMPLE; // 1200

    const f32x4* p4 = (const f32x4*)(pred + (size_t)b * NELEM) + (size_t)chunk * f4_per_block;
    const f32x4* t4 = (const f32x4*)(targ + (size_t)b * NELEM) + (size_t)chunk * f4_per_block;

    float s1 = 0.f, s2 = 0.f, c = 0.f;

    // 1200 = 4*256 + 176. Fully unroll the 4 main strides so all 8 dwordx4
    // loads are in flight before the first use (read-once data -> nt loads).
    f32x4 pr[4], tr[4];
    #pragma unroll
    for (int k = 0; k < 4; ++k) {
        const int i = tid + k * THREADS;
        pr[k] = __builtin_nontemporal_load(p4 + i);
        tr[k] = __builtin_nontemporal_load(t4 + i);
    }
    #pragma unroll
    for (int k = 0; k < 4; ++k) accum4(pr[k], tr[k], s1, s2, c);

    if (tid < f4_per_block - 4 * THREADS) {   // tail: 176 threads
        const int i = tid + 4 * THREADS;
        f32x4 p = __builtin_nontemporal_load(p4 + i);
        f32x4 t = __builtin_nontemporal_load(t4 + i);
        accum4(p, t, s1, s2, c);
    }

    // wave-64 reduction
    #pragma unroll
    for (int off = 32; off > 0; off >>= 1) {
        s1 += __shfl_down(s1, off);
        s2 += __shfl_down(s2, off);
        c  += __shfl_down(c,  off);
    }

    __shared__ float sh1[THREADS / 64];
    __shared__ float sh2[THREADS / 64];
    __shared__ float shc[THREADS / 64];
    const int wave = tid >> 6;
    if ((tid & 63) == 0) { sh1[wave] = s1; sh2[wave] = s2; shc[wave] = c; }
    __syncthreads();

    if (tid == 0) {
        float a1 = 0.f, a2 = 0.f, ac = 0.f;
        #pragma unroll
        for (int w = 0; w < THREADS / 64; ++w) { a1 += sh1[w]; a2 += sh2[w]; ac += shc[w]; }
        ws[b * BLOCKS_PER_SAMPLE + chunk] = make_float4(a1, a2, ac, 0.f);
    }
}

// One block, 1024 threads. Each sample has 64 partials; thread t owns
// sample = t>>5, lane32 = t&31, and folds chunks {lane32, lane32+32} first.
__global__ __launch_bounds__(1024)
void sill_final(const float4* __restrict__ ws, float* __restrict__ out) {
    const int t      = threadIdx.x;
    const int sample = t >> 5;
    const int l      = t & 31;

    float4 a = ws[sample * BLOCKS_PER_SAMPLE + l];
    float4 b = ws[sample * BLOCKS_PER_SAMPLE + l + 32];
    float px = a.x + b.x;
    float py = a.y + b.y;
    float pz = a.z + b.z;

    // reduce the 32 lanes of each sample (width-32 shuffles stay within the sample)
    #pragma unroll
    for (int off = 16; off > 0; off >>= 1) {
        px += __shfl_down(px, off, 32);
        py += __shfl_down(py, off, 32);
        pz += __shfl_down(pz, off, 32);
    }

    __shared__ float ps_sh[NSAMP];
    if (l == 0) {
        float cnt = pz;
        float sc  = fmaxf(cnt, 1.f);
        float ml  = px / sc;
        float ms  = py / sc;
        float ps  = ms - LAM * ml * ml;
        ps_sh[sample] = (cnt > 0.f) ? ps : 0.f;
    }
    __syncthreads();

    if (t < 64) {
        float v = (t < NSAMP) ? ps_sh[t] : 0.f;
        #pragma unroll
        for (int off = 32; off > 0; off >>= 1) v += __shfl_down(v, off);
        if (t == 0) out[0] = v / (float)NSAMP;
    }
}

extern "C" void kernel_launch(void* const* d_in, const int* in_sizes, int n_in,
                              void* d_out, int out_size, void* d_ws, size_t ws_size,
                              hipStream_t stream) {
    const float* pred = (const float*)d_in[0];
    const float* targ = (const float*)d_in[1];
    float* out  = (float*)d_out;
    float4* ws  = (float4*)d_ws;

    dim3 grid(BLOCKS_PER_SAMPLE, NSAMP);
    sill_partial<<<grid, THREADS, 0, stream>>>(pred, targ, ws);
    sill_final<<<1, 1024, 0, stream>>>(ws, out);
}